// Round 3
// baseline (459.071 us; speedup 1.0000x reference)
//
#include <hip/hip_runtime.h>
#include <cstdint>
#include <cstddef>

#define DI __device__ __forceinline__

typedef __attribute__((ext_vector_type(8))) short short8;
typedef __attribute__((ext_vector_type(4))) float floatx4;

static constexpr int BATCH = 16384;
static constexpr int H = 1024;
static constexpr int NT = H / 64;       // K-tiles of 64
static constexpr int HALF = 128 * 64;   // ushorts per 256-tile half (16 KB) [K2]

DI unsigned short f32_to_bf16_bits(float x) {
  union { float f; unsigned int u; } c; c.f = x;
  unsigned int r = c.u + 0x7fffu + ((c.u >> 16) & 1u);
  return (unsigned short)(r >> 16);
}

// ------------- K0: transpose + cast both weights in ONE launch -------------
__global__ __launch_bounds__(256) void transpose_cast2_kernel(const float* __restrict__ Wur,
                                                              const float* __restrict__ U,
                                                              unsigned short* __restrict__ WrT,
                                                              unsigned short* __restrict__ UT) {
  __shared__ float tile[32][33];
  const float* in;
  unsigned short* out;
  int src_stride, src_col0;
  if (blockIdx.z == 0) {
    in = Wur; out = WrT; src_stride = 2 * H; src_col0 = H;
  } else {
    in = U; out = UT; src_stride = H; src_col0 = 0;
  }
  const int bx = blockIdx.x * 32;
  const int by = blockIdx.y * 32;
  const int tx = threadIdx.x;
  const int ty = threadIdx.y;
#pragma unroll
  for (int i = 0; i < 32; i += 8)
    tile[ty + i][tx] = in[(size_t)(bx + ty + i) * src_stride + src_col0 + by + tx];
  __syncthreads();
#pragma unroll
  for (int i = 0; i < 32; i += 8)
    out[(size_t)(by + ty + i) * H + bx + tx] = f32_to_bf16_bits(tile[tx][ty + i]);
}

// ---------------- K1: G = prev@WrT^T -> reset -> X (bf16) ------------------
// 128x128 tile, BK=64, double-buffered LDS. A (prev) is fp32 in HBM: staged
// via regs with fused RNE bf16 cast (kills the standalone cast kernel and the
// prevb round-trip: net -64 MB HBM). B staged via global_load_lds (bf16).
// Per tile: issue A-loads(t+1) + B-gloads(t+1) into buf^1 | frag reads + 64
// MFMA on buf | pack+ds_write A | __syncthreads (drains vmcnt+lgkm).
// Race check: reads touch buf only, writes touch buf^1 only; barrier orders
// the swap; own/others' frag ds_reads complete at barrier (lgkmcnt(0)).
__global__ __launch_bounds__(256, 2) void gemm_k1(const float* __restrict__ prevf,
                                                  const unsigned short* __restrict__ Bt,
                                                  const float* __restrict__ inp,
                                                  unsigned short* __restrict__ Xout) {
  __shared__ __align__(16) unsigned short ldsA[2][128 * 64];  // 16 KB x2
  __shared__ __align__(16) unsigned short ldsB[2][128 * 64];  // 16 KB x2

  const int tid = threadIdx.x;
  const int lane = tid & 63;
  const int wave = tid >> 6;
  const int wm = wave >> 1;
  const int wn = wave & 1;
  const int q = lane >> 4;
  const int l16 = lane & 15;

  // XCD-chunked bijective swizzle (1024 blocks, 128 contiguous per XCD).
  const int sid = blockIdx.y * gridDim.x + blockIdx.x;
  const int lid = (sid & 7) * 128 + (sid >> 3);
  const int bx = lid & 7;
  const int by = lid >> 3;
  const int blockM = by * 128;
  const int blockN = bx * 128;

  // A staging constants: phys chunk c (16B bf16) at row r=c>>3, pc=c&7 holds
  // logical k-chunk klog = pc ^ (r&7) (same involution as the read path).
  int aRow[4], aKlog[4], bSrc[4], bDst[4];
#pragma unroll
  for (int j = 0; j < 4; ++j) {
    const int c = j * 256 + tid;
    const int r = c >> 3;
    aRow[j] = r;
    aKlog[j] = ((c & 7) ^ (r & 7)) * 8;
    bSrc[j] = r * H + aKlog[j];               // B uses same swizzled source
    bDst[j] = (j * 256 + (wave << 6)) * 8;    // wave-uniform chunk base
  }

  auto issueA = [&](int kt, float4* st) {
#pragma unroll
    for (int j = 0; j < 4; ++j) {
      const float* s = prevf + (size_t)(blockM + aRow[j]) * H + kt + aKlog[j];
      st[2 * j] = *reinterpret_cast<const float4*>(s);
      st[2 * j + 1] = *reinterpret_cast<const float4*>(s + 4);
    }
  };
  auto issueB = [&](int kt, int buf) {
#pragma unroll
    for (int j = 0; j < 4; ++j) {
      __builtin_amdgcn_global_load_lds(
          (const __attribute__((address_space(1))) unsigned int*)(Bt + (size_t)blockN * H + kt + bSrc[j]),
          (__attribute__((address_space(3))) unsigned int*)(&ldsB[buf][bDst[j]]), 16, 0, 0);
    }
  };
  auto writeA = [&](const float4* st, int buf) {
#pragma unroll
    for (int j = 0; j < 4; ++j) {
      const int c = j * 256 + tid;
      short8 o;
      o[0] = (short)f32_to_bf16_bits(st[2 * j].x);
      o[1] = (short)f32_to_bf16_bits(st[2 * j].y);
      o[2] = (short)f32_to_bf16_bits(st[2 * j].z);
      o[3] = (short)f32_to_bf16_bits(st[2 * j].w);
      o[4] = (short)f32_to_bf16_bits(st[2 * j + 1].x);
      o[5] = (short)f32_to_bf16_bits(st[2 * j + 1].y);
      o[6] = (short)f32_to_bf16_bits(st[2 * j + 1].z);
      o[7] = (short)f32_to_bf16_bits(st[2 * j + 1].w);
      *reinterpret_cast<short8*>(&ldsA[buf][c * 8]) = o;
    }
  };

  floatx4 acc[4][4] = {};
  float4 st[8];

  // prologue: stage tile 0 into buf 0
  issueA(0, st);
  issueB(0, 0);
  writeA(st, 0);  // compiler inserts vmcnt waits for st deps
  __syncthreads();

  for (int t = 0; t < NT; ++t) {
    const int cur = t & 1;
    const int kn = ((t + 1) & (NT - 1)) * 64;  // last iter wraps (harmless)
    issueA(kn, st);
    issueB(kn, cur ^ 1);

    // ---- compute on buf cur: 2 k-steps of 32, 16 MFMAs each
#pragma unroll
    for (int ks = 0; ks < 2; ++ks) {
      short8 af[4], bfr[4];
#pragma unroll
      for (int i = 0; i < 4; ++i) {
        const int r = wm * 64 + i * 16 + l16;
        const int ch = ks * 4 + q;
        af[i] = *(const short8*)&ldsA[cur][(r * 8 + (ch ^ (r & 7))) * 8];
      }
#pragma unroll
      for (int j = 0; j < 4; ++j) {
        const int r = wn * 64 + j * 16 + l16;
        const int ch = ks * 4 + q;
        bfr[j] = *(const short8*)&ldsB[cur][(r * 8 + (ch ^ (r & 7))) * 8];
      }
#pragma unroll
      for (int i = 0; i < 4; ++i)
#pragma unroll
        for (int j = 0; j < 4; ++j)
          acc[i][j] = __builtin_amdgcn_mfma_f32_16x16x32_bf16(af[i], bfr[j], acc[i][j], 0, 0, 0);
    }

    writeA(st, cur ^ 1);
    __syncthreads();  // drains vmcnt (B gloads) + lgkm (A writes, frag reads)
  }

  // ---- epilogue (EPI0): reset = sigmoid(G + gate_r); X = state_inp * reset
#pragma unroll
  for (int i = 0; i < 4; ++i) {
    const int gr0 = blockM + wm * 64 + i * 16 + q * 4;
#pragma unroll
    for (int j = 0; j < 4; ++j) {
      const int gcol = blockN + wn * 64 + j * 16 + l16;
#pragma unroll
      for (int rg = 0; rg < 4; ++rg) {
        const int gr = gr0 + rg;
        const float z = acc[i][j][rg] + inp[(size_t)gr * (3 * H) + 2 * H + gcol];
        const float rst = 1.0f / (1.0f + __expf(-z));
        const float x = inp[(size_t)gr * (3 * H) + gcol] * rst;
        Xout[(size_t)gr * H + gcol] = f32_to_bf16_bits(x);
      }
    }
  }
}

// ------------------- fragment loaders for K2 (XOR chunk swizzle) -----------
DI void ld8(short8* fr, const unsigned short* base, int wofs, int l16, int q) {
  const int x7 = l16 & 7;
#pragma unroll
  for (int f = 0; f < 4; ++f) {
    const int lr = 32 * f + wofs + l16;
#pragma unroll
    for (int ks = 0; ks < 2; ++ks)
      fr[f * 2 + ks] = *(const short8*)&base[lr * 64 + (((ks * 4 + q) ^ x7) * 8)];
  }
}
DI void ld4(short8* fr, const unsigned short* base, int wofs, int l16, int q) {
  const int x7 = l16 & 7;
#pragma unroll
  for (int jj = 0; jj < 2; ++jj) {
    const int lc = 64 * jj + wofs + l16;
#pragma unroll
    for (int ks = 0; ks < 2; ++ks)
      fr[jj * 2 + ks] = *(const short8*)&base[lc * 64 + (((ks * 4 + q) ^ x7) * 8)];
  }
}

template <int IO, int JO>
DI void mma16(floatx4 (&acc)[8][4], const short8* af, const short8* bf) {
#pragma unroll
  for (int ks = 0; ks < 2; ++ks)
#pragma unroll
    for (int f = 0; f < 4; ++f)
#pragma unroll
      for (int jj = 0; jj < 2; ++jj)
        acc[IO + f][JO + jj] = __builtin_amdgcn_mfma_f32_16x16x32_bf16(
            af[f * 2 + ks], bf[jj * 2 + ks], acc[IO + f][JO + jj], 0, 0, 0);
}

// ---------------- K2: 256x256 8-wave 4-phase pipelined GEMM ----------------
// P = X@UT^T -> out = mask*(tanh(P+s)+1) + prev.  (verified round 2)
__global__ __launch_bounds__(512, 2) void gemm_k2(const unsigned short* __restrict__ A,
                                                  const unsigned short* __restrict__ Bt,
                                                  const float* __restrict__ inp,
                                                  const float* __restrict__ prev,
                                                  const float* __restrict__ mask,
                                                  float* __restrict__ Out) {
  __shared__ __align__(16) unsigned short ldsA[2 * 2 * HALF];
  __shared__ __align__(16) unsigned short ldsB[2 * 2 * HALF];

  const int tid = threadIdx.x;
  const int lane = tid & 63;
  const int w = tid >> 6;
  const int wm16 = (w >> 2) * 16;
  const int wn16 = (w & 3) * 16;
  const int q = lane >> 4;
  const int l16 = lane & 15;

  const int sid = blockIdx.y * gridDim.x + blockIdx.x;
  const int lid = (sid & 7) * 32 + (sid >> 3);
  const int blockN = (lid & 3) * 256;
  const int blockM = (lid >> 2) * 256;

  int srcoff[2], dstch[2];
#pragma unroll
  for (int n = 0; n < 2; ++n) {
    const int c = n * 512 + tid;
    const int r = c >> 3;
    const int gc = (c & 7) ^ (r & 7);
    srcoff[n] = r * H + gc * 8;
    dstch[n] = n * 512 + w * 64;
  }

  const unsigned short* Ab = A + (size_t)blockM * H;
  const unsigned short* Bb = Bt + (size_t)blockN * H;

  auto stage = [&](const unsigned short* gsrc, unsigned short* ldst) {
#pragma unroll
    for (int n = 0; n < 2; ++n) {
      __builtin_amdgcn_global_load_lds(
          (const __attribute__((address_space(1))) unsigned int*)(gsrc + srcoff[n]),
          (__attribute__((address_space(3))) unsigned int*)(ldst + dstch[n] * 8), 16, 0, 0);
    }
  };

  floatx4 acc[8][4] = {};
  short8 af[8], bf0[4], bf1[4];

  stage(Ab, ldsA);
  stage(Bb, ldsB);
  stage(Bb + 128 * H, ldsB + HALF);
  stage(Ab + 128 * H, ldsA + HALF);
  asm volatile("s_waitcnt vmcnt(4)" ::: "memory");
  __builtin_amdgcn_s_barrier();

  for (int t = 0; t < NT; ++t) {
    const int cur = t & 1;
    const int kn = ((t + 1) & (NT - 1)) * 64;
    const unsigned short* lAc = ldsA + cur * 2 * HALF;
    const unsigned short* lBc = ldsB + cur * 2 * HALF;
    unsigned short* lAn = ldsA + (cur ^ 1) * 2 * HALF;
    unsigned short* lBn = ldsB + (cur ^ 1) * 2 * HALF;

    ld8(af, lAc, wm16, l16, q);
    ld4(bf0, lBc, wn16, l16, q);
    stage(Ab + kn, lAn);
    __builtin_amdgcn_s_barrier();
    __builtin_amdgcn_s_setprio(1);
    mma16<0, 0>(acc, af, bf0);
    __builtin_amdgcn_s_setprio(0);
    asm volatile("s_waitcnt vmcnt(4)" ::: "memory");
    __builtin_amdgcn_s_barrier();

    ld4(bf1, lBc + HALF, wn16, l16, q);
    stage(Bb + kn, lBn);
    __builtin_amdgcn_s_barrier();
    __builtin_amdgcn_s_setprio(1);
    mma16<0, 2>(acc, af, bf1);
    __builtin_amdgcn_s_setprio(0);
    asm volatile("s_waitcnt vmcnt(4)" ::: "memory");
    __builtin_amdgcn_s_barrier();

    ld8(af, lAc + HALF, wm16, l16, q);
    stage(Bb + 128 * H + kn, lBn + HALF);
    __builtin_amdgcn_s_barrier();
    __builtin_amdgcn_s_setprio(1);
    mma16<4, 2>(acc, af, bf1);
    __builtin_amdgcn_s_setprio(0);
    __builtin_amdgcn_s_barrier();

    stage(Ab + 128 * H + kn, lAn + HALF);
    __builtin_amdgcn_s_barrier();
    __builtin_amdgcn_s_setprio(1);
    mma16<4, 0>(acc, af, bf0);
    __builtin_amdgcn_s_setprio(0);
    asm volatile("s_waitcnt vmcnt(4)" ::: "memory");
    __builtin_amdgcn_s_barrier();
  }

#pragma unroll
  for (int i = 0; i < 8; ++i) {
    const int gr0 = blockM + 128 * (i >> 2) + 32 * (i & 3) + wm16 + q * 4;
#pragma unroll
    for (int j = 0; j < 4; ++j) {
      const int gcol = blockN + 128 * (j >> 1) + 64 * (j & 1) + wn16 + l16;
#pragma unroll
      for (int rg = 0; rg < 4; ++rg) {
        const int gr = gr0 + rg;
        const float s = inp[(size_t)gr * (3 * H) + gcol];
        const float a = acc[i][j][rg] + s;
        const float ns = 1.0f - 2.0f / (__expf(2.0f * a) + 1.0f);
        const float m = mask[gr];
        Out[(size_t)gr * H + gcol] = m * (ns + 1.0f) + prev[(size_t)gr * H + gcol];
      }
    }
  }
}

extern "C" void kernel_launch(void* const* d_in, const int* in_sizes, int n_in,
                              void* d_out, int out_size, void* d_ws, size_t ws_size,
                              hipStream_t stream) {
  const float* inp = (const float*)d_in[0];    // (B, 3H)
  const float* prev = (const float*)d_in[1];   // (B, H)
  const float* mask = (const float*)d_in[2];   // (B,)
  const float* Wur = (const float*)d_in[3];    // (H, 2H)
  const float* U = (const float*)d_in[4];      // (H, H)
  float* out = (float*)d_out;

  char* ws = (char*)d_ws;
  unsigned short* Xb = (unsigned short*)ws;                             // B*H bf16 (32 MB)
  unsigned short* WrT = (unsigned short*)(ws + (size_t)BATCH * H * 2);  // H*H bf16 (2 MB)
  unsigned short* UT = WrT + (size_t)H * H;                             // H*H bf16 (2 MB)

  // K0: weight transposes (tiny)
  transpose_cast2_kernel<<<dim3(H / 32, H / 32, 2), dim3(32, 8), 0, stream>>>(Wur, U, WrT, UT);

  // K1: G = prev@Wr -> reset -> X (bf16); prev cast fused into A-staging.
  gemm_k1<<<dim3(H / 128, BATCH / 128), 256, 0, stream>>>(prev, WrT, inp, Xb);

  // K2: P = X@U -> out
  gemm_k2<<<dim3(H / 256, BATCH / 256), 512, 0, stream>>>(Xb, UT, inp, prev, mask, out);
}

// Round 4
// 442.518 us; speedup vs baseline: 1.0374x; 1.0374x over previous
//
#include <hip/hip_runtime.h>
#include <cstdint>
#include <cstddef>

#define DI __device__ __forceinline__

typedef __attribute__((ext_vector_type(8))) short short8;
typedef __attribute__((ext_vector_type(4))) float floatx4;

static constexpr int BATCH = 16384;
static constexpr int H = 1024;
static constexpr int NT = H / 64;       // K-tiles of 64
static constexpr int HALF = 128 * 64;   // ushorts per 256-tile half (16 KB) [K2]

DI unsigned short f32_to_bf16_bits(float x) {
  union { float f; unsigned int u; } c; c.f = x;
  unsigned int r = c.u + 0x7fffu + ((c.u >> 16) & 1u);
  return (unsigned short)(r >> 16);
}

// ------------- K0: transpose + cast both weights in ONE launch -------------
__global__ __launch_bounds__(256) void transpose_cast2_kernel(const float* __restrict__ Wur,
                                                              const float* __restrict__ U,
                                                              unsigned short* __restrict__ WrT,
                                                              unsigned short* __restrict__ UT) {
  __shared__ float tile[32][33];
  const float* in;
  unsigned short* out;
  int src_stride, src_col0;
  if (blockIdx.z == 0) {
    in = Wur; out = WrT; src_stride = 2 * H; src_col0 = H;
  } else {
    in = U; out = UT; src_stride = H; src_col0 = 0;
  }
  const int bx = blockIdx.x * 32;
  const int by = blockIdx.y * 32;
  const int tx = threadIdx.x;
  const int ty = threadIdx.y;
#pragma unroll
  for (int i = 0; i < 32; i += 8)
    tile[ty + i][tx] = in[(size_t)(bx + ty + i) * src_stride + src_col0 + by + tx];
  __syncthreads();
#pragma unroll
  for (int i = 0; i < 32; i += 8)
    out[(size_t)(by + ty + i) * H + bx + tx] = f32_to_bf16_bits(tile[tx][ty + i]);
}

// ---------------- K1: G = prev@WrT^T -> reset -> X (bf16) ------------------
// A (prev) staged as RAW FP32 via global_load_lds (DMA, no reg round-trip —
// R3's reg-staging stall is gone); bf16 convert happens at fragment-read in
// the VALU (17% busy -> ample idle slots). Kills the standalone cast kernel
// and the prevb round-trip: net -64 MB HBM, -1 launch. Numerics bit-identical
// to the cast-kernel path (same RNE bit-math, same accumulation order).
// LDS: A fp32 32 KB + B bf16 16 KB = 48 KB single-buffer -> 3 blocks/CU.
// m97-class loop: stage -> vmcnt(0)+syncthreads -> compute -> syncthreads.
__global__ __launch_bounds__(256, 3) void gemm_k1(const float* __restrict__ prevf,
                                                  const unsigned short* __restrict__ Bt,
                                                  const float* __restrict__ inp,
                                                  unsigned short* __restrict__ Xout) {
  __shared__ __align__(16) float ldsAf[128 * 64];          // 32 KB fp32
  __shared__ __align__(16) unsigned short ldsB[128 * 64];  // 16 KB bf16

  const int tid = threadIdx.x;
  const int lane = tid & 63;
  const int wave = tid >> 6;
  const int wm = wave >> 1;
  const int wn = wave & 1;
  const int q = lane >> 4;
  const int l16 = lane & 15;

  // XCD-chunked bijective swizzle (1024 blocks, 128 contiguous per XCD).
  const int sid = blockIdx.y * gridDim.x + blockIdx.x;
  const int lid = (sid & 7) * 128 + (sid >> 3);
  const int bx = lid & 7;
  const int by = lid >> 3;
  const int blockM = by * 128;
  const int blockN = bx * 128;

  // A: 2048 chunks of 16B (4 floats); chunk c at row r=c>>4, phys pc=c&15
  // holds logical chunk lc = pc ^ (r&15) (involution; same XOR on read side).
  // B: 1024 chunks of 16B (8 bf16); r=c>>3, pc=c&7, lc = pc ^ (r&7).
  int aSrc[8], aDst[8], bSrc[4], bDst[4];
#pragma unroll
  for (int j = 0; j < 8; ++j) {
    const int c = j * 256 + tid;
    const int r = c >> 4;
    aSrc[j] = r * H + ((c & 15) ^ (r & 15)) * 4;   // float offset from (blockM, kt)
    aDst[j] = (j * 256 + (wave << 6)) * 4;         // wave-uniform float base (+lane*16B by HW)
  }
#pragma unroll
  for (int j = 0; j < 4; ++j) {
    const int c = j * 256 + tid;
    const int r = c >> 3;
    bSrc[j] = r * H + ((c & 7) ^ (r & 7)) * 8;     // ushort offset
    bDst[j] = (j * 256 + (wave << 6)) * 8;
  }

  floatx4 acc[4][4] = {};

  for (int kt = 0; kt < H; kt += 64) {
    // ---- stage tile (DMA path for both operands)
#pragma unroll
    for (int j = 0; j < 8; ++j) {
      __builtin_amdgcn_global_load_lds(
          (const __attribute__((address_space(1))) unsigned int*)(prevf + (size_t)blockM * H + kt + aSrc[j]),
          (__attribute__((address_space(3))) unsigned int*)(&ldsAf[aDst[j]]), 16, 0, 0);
    }
#pragma unroll
    for (int j = 0; j < 4; ++j) {
      __builtin_amdgcn_global_load_lds(
          (const __attribute__((address_space(1))) unsigned int*)(Bt + (size_t)blockN * H + kt + bSrc[j]),
          (__attribute__((address_space(3))) unsigned int*)(&ldsB[bDst[j]]), 16, 0, 0);
    }
    asm volatile("s_waitcnt vmcnt(0)" ::: "memory");
    __syncthreads();

    // ---- compute: 2 k-steps of 32, 16 MFMAs each
#pragma unroll
    for (int ks = 0; ks < 2; ++ks) {
      short8 af[4], bfr[4];
#pragma unroll
      for (int i = 0; i < 4; ++i) {
        const int lr = wm * 64 + i * 16 + l16;
        const int lc0 = (ks * 4 + q) * 2;          // even logical chunk
        const int x = lr & 15;
        const float4 lo = *(const float4*)&ldsAf[lr * 64 + ((lc0 ^ x) * 4)];
        const float4 hi = *(const float4*)&ldsAf[lr * 64 + (((lc0 + 1) ^ x) * 4)];
        short8 a;
        a[0] = (short)f32_to_bf16_bits(lo.x);
        a[1] = (short)f32_to_bf16_bits(lo.y);
        a[2] = (short)f32_to_bf16_bits(lo.z);
        a[3] = (short)f32_to_bf16_bits(lo.w);
        a[4] = (short)f32_to_bf16_bits(hi.x);
        a[5] = (short)f32_to_bf16_bits(hi.y);
        a[6] = (short)f32_to_bf16_bits(hi.z);
        a[7] = (short)f32_to_bf16_bits(hi.w);
        af[i] = a;
      }
#pragma unroll
      for (int j = 0; j < 4; ++j) {
        const int r = wn * 64 + j * 16 + l16;
        const int ch = ks * 4 + q;
        bfr[j] = *(const short8*)&ldsB[(r * 8 + (ch ^ (r & 7))) * 8];
      }
#pragma unroll
      for (int i = 0; i < 4; ++i)
#pragma unroll
        for (int j = 0; j < 4; ++j)
          acc[i][j] = __builtin_amdgcn_mfma_f32_16x16x32_bf16(af[i], bfr[j], acc[i][j], 0, 0, 0);
    }
    __syncthreads();
  }

  // ---- epilogue (EPI0): reset = sigmoid(G + gate_r); X = state_inp * reset
#pragma unroll
  for (int i = 0; i < 4; ++i) {
    const int gr0 = blockM + wm * 64 + i * 16 + q * 4;
#pragma unroll
    for (int j = 0; j < 4; ++j) {
      const int gcol = blockN + wn * 64 + j * 16 + l16;
#pragma unroll
      for (int rg = 0; rg < 4; ++rg) {
        const int gr = gr0 + rg;
        const float z = acc[i][j][rg] + inp[(size_t)gr * (3 * H) + 2 * H + gcol];
        const float rst = 1.0f / (1.0f + __expf(-z));
        const float x = inp[(size_t)gr * (3 * H) + gcol] * rst;
        Xout[(size_t)gr * H + gcol] = f32_to_bf16_bits(x);
      }
    }
  }
}

// ------------------- fragment loaders for K2 (XOR chunk swizzle) -----------
DI void ld8(short8* fr, const unsigned short* base, int wofs, int l16, int q) {
  const int x7 = l16 & 7;
#pragma unroll
  for (int f = 0; f < 4; ++f) {
    const int lr = 32 * f + wofs + l16;
#pragma unroll
    for (int ks = 0; ks < 2; ++ks)
      fr[f * 2 + ks] = *(const short8*)&base[lr * 64 + (((ks * 4 + q) ^ x7) * 8)];
  }
}
DI void ld4(short8* fr, const unsigned short* base, int wofs, int l16, int q) {
  const int x7 = l16 & 7;
#pragma unroll
  for (int jj = 0; jj < 2; ++jj) {
    const int lc = 64 * jj + wofs + l16;
#pragma unroll
    for (int ks = 0; ks < 2; ++ks)
      fr[jj * 2 + ks] = *(const short8*)&base[lc * 64 + (((ks * 4 + q) ^ x7) * 8)];
  }
}

template <int IO, int JO>
DI void mma16(floatx4 (&acc)[8][4], const short8* af, const short8* bf) {
#pragma unroll
  for (int ks = 0; ks < 2; ++ks)
#pragma unroll
    for (int f = 0; f < 4; ++f)
#pragma unroll
      for (int jj = 0; jj < 2; ++jj)
        acc[IO + f][JO + jj] = __builtin_amdgcn_mfma_f32_16x16x32_bf16(
            af[f * 2 + ks], bf[jj * 2 + ks], acc[IO + f][JO + jj], 0, 0, 0);
}

// ---------------- K2: 256x256 8-wave 4-phase pipelined GEMM ----------------
// P = X@UT^T -> out = mask*(tanh(P+s)+1) + prev.  (verified rounds 2 & 3)
__global__ __launch_bounds__(512, 2) void gemm_k2(const unsigned short* __restrict__ A,
                                                  const unsigned short* __restrict__ Bt,
                                                  const float* __restrict__ inp,
                                                  const float* __restrict__ prev,
                                                  const float* __restrict__ mask,
                                                  float* __restrict__ Out) {
  __shared__ __align__(16) unsigned short ldsA[2 * 2 * HALF];
  __shared__ __align__(16) unsigned short ldsB[2 * 2 * HALF];

  const int tid = threadIdx.x;
  const int lane = tid & 63;
  const int w = tid >> 6;
  const int wm16 = (w >> 2) * 16;
  const int wn16 = (w & 3) * 16;
  const int q = lane >> 4;
  const int l16 = lane & 15;

  const int sid = blockIdx.y * gridDim.x + blockIdx.x;
  const int lid = (sid & 7) * 32 + (sid >> 3);
  const int blockN = (lid & 3) * 256;
  const int blockM = (lid >> 2) * 256;

  int srcoff[2], dstch[2];
#pragma unroll
  for (int n = 0; n < 2; ++n) {
    const int c = n * 512 + tid;
    const int r = c >> 3;
    const int gc = (c & 7) ^ (r & 7);
    srcoff[n] = r * H + gc * 8;
    dstch[n] = n * 512 + w * 64;
  }

  const unsigned short* Ab = A + (size_t)blockM * H;
  const unsigned short* Bb = Bt + (size_t)blockN * H;

  auto stage = [&](const unsigned short* gsrc, unsigned short* ldst) {
#pragma unroll
    for (int n = 0; n < 2; ++n) {
      __builtin_amdgcn_global_load_lds(
          (const __attribute__((address_space(1))) unsigned int*)(gsrc + srcoff[n]),
          (__attribute__((address_space(3))) unsigned int*)(ldst + dstch[n] * 8), 16, 0, 0);
    }
  };

  floatx4 acc[8][4] = {};
  short8 af[8], bf0[4], bf1[4];

  stage(Ab, ldsA);
  stage(Bb, ldsB);
  stage(Bb + 128 * H, ldsB + HALF);
  stage(Ab + 128 * H, ldsA + HALF);
  asm volatile("s_waitcnt vmcnt(4)" ::: "memory");
  __builtin_amdgcn_s_barrier();

  for (int t = 0; t < NT; ++t) {
    const int cur = t & 1;
    const int kn = ((t + 1) & (NT - 1)) * 64;
    const unsigned short* lAc = ldsA + cur * 2 * HALF;
    const unsigned short* lBc = ldsB + cur * 2 * HALF;
    unsigned short* lAn = ldsA + (cur ^ 1) * 2 * HALF;
    unsigned short* lBn = ldsB + (cur ^ 1) * 2 * HALF;

    ld8(af, lAc, wm16, l16, q);
    ld4(bf0, lBc, wn16, l16, q);
    stage(Ab + kn, lAn);
    __builtin_amdgcn_s_barrier();
    __builtin_amdgcn_s_setprio(1);
    mma16<0, 0>(acc, af, bf0);
    __builtin_amdgcn_s_setprio(0);
    asm volatile("s_waitcnt vmcnt(4)" ::: "memory");
    __builtin_amdgcn_s_barrier();

    ld4(bf1, lBc + HALF, wn16, l16, q);
    stage(Bb + kn, lBn);
    __builtin_amdgcn_s_barrier();
    __builtin_amdgcn_s_setprio(1);
    mma16<0, 2>(acc, af, bf1);
    __builtin_amdgcn_s_setprio(0);
    asm volatile("s_waitcnt vmcnt(4)" ::: "memory");
    __builtin_amdgcn_s_barrier();

    ld8(af, lAc + HALF, wm16, l16, q);
    stage(Bb + 128 * H + kn, lBn + HALF);
    __builtin_amdgcn_s_barrier();
    __builtin_amdgcn_s_setprio(1);
    mma16<4, 2>(acc, af, bf1);
    __builtin_amdgcn_s_setprio(0);
    __builtin_amdgcn_s_barrier();

    stage(Ab + 128 * H + kn, lAn + HALF);
    __builtin_amdgcn_s_barrier();
    __builtin_amdgcn_s_setprio(1);
    mma16<4, 0>(acc, af, bf0);
    __builtin_amdgcn_s_setprio(0);
    asm volatile("s_waitcnt vmcnt(4)" ::: "memory");
    __builtin_amdgcn_s_barrier();
  }

#pragma unroll
  for (int i = 0; i < 8; ++i) {
    const int gr0 = blockM + 128 * (i >> 2) + 32 * (i & 3) + wm16 + q * 4;
#pragma unroll
    for (int j = 0; j < 4; ++j) {
      const int gcol = blockN + 128 * (j >> 1) + 64 * (j & 1) + wn16 + l16;
#pragma unroll
      for (int rg = 0; rg < 4; ++rg) {
        const int gr = gr0 + rg;
        const float s = inp[(size_t)gr * (3 * H) + gcol];
        const float a = acc[i][j][rg] + s;
        const float ns = 1.0f - 2.0f / (__expf(2.0f * a) + 1.0f);
        const float m = mask[gr];
        Out[(size_t)gr * H + gcol] = m * (ns + 1.0f) + prev[(size_t)gr * H + gcol];
      }
    }
  }
}

extern "C" void kernel_launch(void* const* d_in, const int* in_sizes, int n_in,
                              void* d_out, int out_size, void* d_ws, size_t ws_size,
                              hipStream_t stream) {
  const float* inp = (const float*)d_in[0];    // (B, 3H)
  const float* prev = (const float*)d_in[1];   // (B, H)
  const float* mask = (const float*)d_in[2];   // (B,)
  const float* Wur = (const float*)d_in[3];    // (H, 2H)
  const float* U = (const float*)d_in[4];      // (H, H)
  float* out = (float*)d_out;

  char* ws = (char*)d_ws;
  unsigned short* Xb = (unsigned short*)ws;                             // B*H bf16 (32 MB)
  unsigned short* WrT = (unsigned short*)(ws + (size_t)BATCH * H * 2);  // H*H bf16 (2 MB)
  unsigned short* UT = WrT + (size_t)H * H;                             // H*H bf16 (2 MB)

  // K0: weight transposes (tiny)
  transpose_cast2_kernel<<<dim3(H / 32, H / 32, 2), dim3(32, 8), 0, stream>>>(Wur, U, WrT, UT);

  // K1: G = prev@Wr -> reset -> X (bf16); prev consumed as fp32 via DMA,
  // cast fused into fragment read (no cast kernel, no prevb round-trip).
  gemm_k1<<<dim3(H / 128, BATCH / 128), 256, 0, stream>>>(prev, WrT, inp, Xb);

  // K2: P = X@U -> out
  gemm_k2<<<dim3(H / 256, BATCH / 256), 512, 0, stream>>>(Xb, UT, inp, prev, mask, out);
}